// Round 22
// baseline (104.921 us; speedup 1.0000x reference)
//
#include <hip/hip_runtime.h>

#define NIMG    4991
#define RIRLEN  3968
#define NT      512          // fallback block: 8 waves
#define NTP     1024         // prep block: 16 waves
#define NTG     256          // gather block: 4 waves (R21 lesson: granularity)
#define NGRPF   16           // fallback blocks per batch
#define GGRP    32           // gather blocks per batch; grid = B*32 = 4096
#define CAP     2048         // fallback staged capacity
#define CAPG    1024         // gather staged capacity (2 windows, ~330 typ)
#define KPT     10           // images per thread, NT=512 path
#define KPTP    5            // images per thread, NTP=1024 path
#define INV_PI  0.31830988618379067f
#define SR_OVER_C 46.647230320699704f   // 16000 / 343

// ---- compile-time compact image-source table: all (x,y,z), |x|+|y|+|z| <= 15 ----
struct Tab { int v[NIMG]; };
static constexpr Tab make_tab() {
    Tab t{};
    int k = 0;
    for (int x = -15; x <= 15; ++x)
        for (int y = -15; y <= 15; ++y)
            for (int z = -15; z <= 15; ++z) {
                int ax = x < 0 ? -x : x;
                int ay = y < 0 ? -y : y;
                int az = z < 0 ? -z : z;
                if (ax + ay + az <= 15)
                    t.v[k++] = (x + 15) | ((y + 15) << 8) | ((z + 15) << 16);
            }
    return t;
}
__constant__ Tab c_tab = make_tab();

static __device__ __forceinline__ int iabs(int v) { return v < 0 ? -v : v; }
static __device__ __forceinline__ int imin(int a, int b) { return a < b ? a : b; }
static __device__ __forceinline__ int imax(int a, int b) { return a > b ? a : b; }

// __builtin_amdgcn_cvt_pkrtz returns __fp16-based ext vector (R10 lesson).
typedef __fp16 f16x2 __attribute__((ext_vector_type(2)));

// ============================================================================
// v29 = v27 with FINE-GRAINED GATHER. R21 bound: prep+gather ~54us, both
// <42.3 (not in top-5) -> gather ~40, prep ~13. Gather is ~4x its issue
// floor and the EVAL phase has sat at 40-50us across occupancy 23->62% --
// the invariant is BLOCK granularity (8-wave blocks, 4/CU resident, 2
// rounds, serial per-block chain + 3x cross-batch work variance). This
// version: gather NT=256 (4 waves), GGRP=32 -> 4096 blocks, ~13KB LDS,
// launch_bounds(256,8) -> 8 blocks/CU resident, 16/CU total. Per-block
// chain halves; drain granularity doubles. Prep/fallback = R21 verbatim.
// Math (verified R9-R21): entry {dstore, Hp} + packed f16 {Hcd,Hsd};
// v(t) = (-1)^t * (Hp + cth0*Hcd + sth0*Hsd) / (t - dstore), |xw|<=40 mask.
// xw==0 impossible (Sterbenz exact / relative nudge di*2^-16).
// ============================================================================

// ---- K1: once-per-batch prep: geometry + bucket-sort into ws ----
__global__ __launch_bounds__(NTP)
void rir_prep(const float* __restrict__ inp, float* __restrict__ out,
              float2* __restrict__ wdh, unsigned* __restrict__ wcs,
              int* __restrict__ offs, int B) {
    const int b    = blockIdx.x;
    const int tid  = threadIdx.x;
    const int lane = tid & 63;
    const int wv   = tid >> 6;
    const int q    = lane & 3;

    __shared__ float s_par[12];
    __shared__ float s_p2[3][32];
    __shared__ float s_at[3][32];
    __shared__ int   s_h4[256][4];
    __shared__ int   s_off[257];

    if (tid < 1024) ((int*)s_h4)[tid] = 0;
    if (tid == 0) {
        const float* ip = inp + b * 12;
        float rx = ip[0], ry = ip[1], rz = ip[2];
        float mx = ip[3] * rx, my = ip[4] * ry, mz = ip[5] * rz;
        float sx = ip[6] * rx, sy = ip[7] * ry, sz = ip[8] * rz;
        float aw = __builtin_fmaf(ip[9],  0.84f, 0.01f);
        float a4 = __builtin_fmaf(ip[10], 0.84f, 0.01f);
        float a5 = __builtin_fmaf(ip[11], 0.84f, 0.01f);
        s_par[0] = rx; s_par[1] = ry; s_par[2] = rz;
        s_par[3] = mx; s_par[4] = my; s_par[5] = mz;
        s_par[6] = sx; s_par[7] = sy; s_par[8] = sz;
        s_par[9]  = 0.5f * __builtin_amdgcn_logf(1.0f - aw);   // log2(tr)
        s_par[10] = 0.5f * __builtin_amdgcn_logf(1.0f - a4);
        s_par[11] = 0.5f * __builtin_amdgcn_logf(1.0f - a5);
        float dx = mx - sx, dy = my - sy, dz = mz - sz;
        out[(size_t)B * RIRLEN + b] = __builtin_fmaf(
            __builtin_sqrtf(dx * dx + dy * dy + dz * dz), SR_OVER_C, 40.0f);
    }
    __syncthreads();

    if (tid < 96) {                          // per-axis tables
        const int axis = tid >> 5;
        const int j    = tid & 31;
        if (j < 31) {
            const int n = j - 15;
            const float rr = s_par[axis];
            const float mm = s_par[3 + axis];
            const float ss = s_par[6 + axis];
            const float iv = (n & 1) ? __builtin_fmaf(rr, (float)(n + 1), -ss)
                                     : __builtin_fmaf(rr, (float)n, ss);
            const float pv = iv - mm;
            s_p2[axis][j] = pv * pv;
            const float e4 = (float)iabs(n >> 1);
            const float e5 = (float)iabs((n + 1) >> 1);
            const float ex = (axis < 2)
                ? (e4 + e5) * s_par[9]
                : __builtin_fmaf(e4, s_par[10], e5 * s_par[11]);
            s_at[axis][j] = __builtin_amdgcn_exp2f(ex);
        }
    }
    __syncthreads();

    // single geometry pass -> registers; histogram returns rank
    float2   edh[KPTP];
    unsigned ecs[KPTP];
    int      enc[KPTP];
    #pragma unroll
    for (int k = 0; k < KPTP; ++k) {
        enc[k] = -1;
        const int idx = tid + k * NTP;
        if (idx < NIMG) {
            const int p  = c_tab.v[idx];
            const int xi = p & 255;
            const int yi = (p >> 8) & 255;
            const int zi = (p >> 16) & 255;
            const float d2   = s_p2[0][xi] + s_p2[1][yi] + s_p2[2][zi];
            const float dist = __builtin_sqrtf(d2);
            const float delay = dist * SR_OVER_C;
            const float di    = __builtin_ceilf(delay);
            const int   ti0   = (int)di - 40;
            if (ti0 < RIRLEN) {
                const int bk = (ti0 + 96) >> 4;                // in [3,253]
                const float att = s_at[0][xi] * s_at[1][yi] * s_at[2][zi];
                const float amp = att * __builtin_amdgcn_rcpf(dist);
                float frac = di - delay;                       // exact (Sterbenz)
                if (frac == 0.0f) frac = di * 1.52587890625e-05f;
                const int dii = (int)di;
                float c1p = amp * __builtin_amdgcn_sinf(0.5f * frac) * INV_PI;
                if (dii & 1) c1p = -c1p;
                const float Hp     = 0.5f * c1p;
                const float dstore = di - frac;
                const float rv = dstore * 0.0125f;
                const float fr = rv - __builtin_floorf(rv);
                const float Hcd = Hp * __builtin_amdgcn_cosf(fr);
                const float Hsd = Hp * __builtin_amdgcn_sinf(fr);
                const f16x2 pk2 = __builtin_amdgcn_cvt_pkrtz(Hcd, Hsd);

                const int rnk = atomicAdd(&s_h4[bk][q], 1);
                enc[k] = (bk << 13) | rnk;
                edh[k] = make_float2(dstore, Hp);
                ecs[k] = __builtin_bit_cast(unsigned, pk2);
            }
        }
    }
    __syncthreads();

    if (wv == 0) {                           // single-wave shuffle scan
        const int l = lane;
        const int4 a0 = *(const int4*)&s_h4[4 * l + 0][0];
        const int4 a1 = *(const int4*)&s_h4[4 * l + 1][0];
        const int4 a2 = *(const int4*)&s_h4[4 * l + 2][0];
        const int4 a3 = *(const int4*)&s_h4[4 * l + 3][0];
        const int c0 = a0.x + a0.y + a0.z + a0.w;
        const int c1 = a1.x + a1.y + a1.z + a1.w;
        const int c2 = a2.x + a2.y + a2.z + a2.w;
        const int c3 = a3.x + a3.y + a3.z + a3.w;
        const int ts = c0 + c1 + c2 + c3;
        int incl = ts;
        #pragma unroll
        for (int d = 1; d < 64; d <<= 1) {
            const int u = __shfl_up(incl, d, 64);
            if (l >= d) incl += u;
        }
        const int base = incl - ts;
        s_off[4 * l + 0] = base;
        s_off[4 * l + 1] = base + c0;
        s_off[4 * l + 2] = base + c0 + c1;
        s_off[4 * l + 3] = base + c0 + c1 + c2;
        if (l == 63) s_off[256] = incl;
    }
    __syncthreads();

    if (tid < 256) {                         // counts -> base cursors
        int run = s_off[tid];
        #pragma unroll
        for (int p = 0; p < 4; ++p) {
            const int c = s_h4[tid][p];
            s_h4[tid][p] = run;
            run += c;
        }
    }
    __syncthreads();

    // scatter to GLOBAL ws (rank + base, plain stores)
    float2*   db = wdh + (size_t)b * NIMG;
    unsigned* cb = wcs + (size_t)b * NIMG;
    #pragma unroll
    for (int k = 0; k < KPTP; ++k) {
        if (enc[k] >= 0) {
            const int bk   = enc[k] >> 13;
            const int slot = s_h4[bk][q] + (enc[k] & 8191);
            db[slot] = edh[k];
            cb[slot] = ecs[k];
        }
    }
    if (tid < 257) offs[b * 257 + tid] = s_off[tid];
}

// ---- K2: fine-grained gather: 4-wave blocks, 2 windows each ----
__global__ __launch_bounds__(NTG, 8)
void rir_gather(const float2* __restrict__ wdh, const unsigned* __restrict__ wcs,
                const int* __restrict__ offs, float* __restrict__ out, int B) {
    const int bx   = blockIdx.x;
    const int b    = bx >> 5;
    const int g    = bx & 31;
    const int tid  = threadIdx.x;
    const int lane = tid & 63;
    const int wv   = tid >> 6;               // 0..3

    __shared__ __align__(16) float2   s_dh[CAPG];   // staged {delay, Hp}  (8KB)
    __shared__ __align__(16) unsigned s_cs[CAPG];   // staged packed f16   (4KB)
    __shared__ float s_acc[2][64];                  // per-window accum

    if (tid < 128) ((float*)s_acc)[tid] = 0.0f;

    // window table (windows wi = g + 32kk, kk<2; buckets 4wi+1..4wi+9)
    const int* ob = offs + b * 257;
    int wlo[2], wlen[2], wpre[2];
    int T = 0, nw = 0;
    #pragma unroll
    for (int kk = 0; kk < 2; ++kk) {
        const int wi = g + 32 * kk;
        wpre[kk] = T;
        if (wi < 62) {
            wlo[kk] = ob[4 * wi + 1];
            int len = ob[4 * wi + 10] - wlo[kk];
            if (T + len > CAPG) len = CAPG - T;  // truncation guard (~impossible)
            if (len < 0) len = 0;
            wlen[kk] = len;
            T += len;
            nw = kk + 1;
        } else { wlo[kk] = 0; wlen[kk] = 0; }
    }

    // stage spans (concatenated) global -> LDS, coalesced within spans
    const float2*   db = wdh + (size_t)b * NIMG;
    const unsigned* cb = wcs + (size_t)b * NIMG;
    for (int j = tid; j < T; j += NTG) {
        const int kk  = (j >= wpre[1] && wlen[1] > 0) ? 1 : 0;
        const int src = wlo[kk] + (j - wpre[kk]);
        s_dh[j] = db[src];
        s_cs[j] = cb[src];
    }
    __syncthreads();

    const int a0r = (T * wv) >> 2;           // this wave's slice [a0r, a1r)
    const int a1r = (T * (wv + 1)) >> 2;

#define EV1(ACC, DLY, HPV, PKU) do {                                         \
        const f16x2 hh = __builtin_bit_cast(f16x2, (PKU));                   \
        const float xw = tf - (DLY);                                         \
        const float pre = __builtin_fmaf(cth0, (float)hh.x,                  \
                              __builtin_fmaf(sth0, (float)hh.y, (HPV)));     \
        const float hm = (__builtin_fabsf(xw) <= 40.0f) ? pre : 0.0f;        \
        ACC = __builtin_fmaf(hm, __builtin_amdgcn_rcpf(xw), ACC);            \
    } while (0)

    #pragma unroll
    for (int kk = 0; kk < 2; ++kk) {
        if (wlen[kk] == 0) continue;
        int       i  = imax(wpre[kk], a0r);
        const int ie = imin(wpre[kk] + wlen[kk], a1r);
        if (i >= ie) continue;

        const int   wi   = g + 32 * kk;
        const int   t    = (wi << 6) + lane;
        const float tf   = (float)t;
        const int   m    = t - (t / 80) * 80;           // t mod 80
        const float cth0 = __builtin_amdgcn_cosf((float)m * 0.0125f);
        const float sth0 = __builtin_amdgcn_sinf((float)m * 0.0125f);

        float acc0 = 0.0f, acc1 = 0.0f;
        while (i < ie && (i & 3)) { EV1(acc0, s_dh[i].x, s_dh[i].y, s_cs[i]); ++i; }
        for (; i + 4 <= ie; i += 4) {        // 4 images / iter = 3 ds_read_b128
            const float4 d0 = *(const float4*)&s_dh[i];
            const float4 d1 = *(const float4*)&s_dh[i + 2];
            const uint4  cc = *(const uint4*)&s_cs[i];
            EV1(acc0, d0.x, d0.y, cc.x); EV1(acc1, d0.z, d0.w, cc.y);
            EV1(acc0, d1.x, d1.y, cc.z); EV1(acc1, d1.z, d1.w, cc.w);
        }
        for (; i < ie; ++i) EV1(acc0, s_dh[i].x, s_dh[i].y, s_cs[i]);

        atomicAdd(&s_acc[kk][lane], acc0 + acc1);
    }
#undef EV1
    __syncthreads();

    if (tid < 64 * nw) {
        const int kk = tid >> 6;
        const int wi = g + 32 * kk;
        const int t  = (wi << 6) + lane;
        const float sl = (lane & 1) ? -1.0f : 1.0f;     // wi*64 even
        out[(size_t)b * RIRLEN + t] = sl * s_acc[kk][lane];
    }
}

// ============================================================================
// Fallback (!use_ws): R19's verified single fused kernel, verbatim.
// ============================================================================
__global__ __launch_bounds__(NT, 8)
void rir_fused(const float* __restrict__ inp, float* __restrict__ out, int B) {
    const int bx   = blockIdx.x;
    const int b    = bx >> 4;
    const int g    = bx & 15;
    const int tid  = threadIdx.x;
    const int lane = tid & 63;
    const int wv   = tid >> 6;
    const int q    = lane & 3;

    __shared__ __align__(16) float2   s_dh[CAP];
    __shared__ __align__(16) unsigned s_cs[CAP];
    __shared__ float    s_par[12];
    __shared__ float    s_p2[3][32];
    __shared__ float    s_at[3][32];
    __shared__ int      s_h4[256][4];
    __shared__ int      s_off[257];
    __shared__ float    s_acc[4][64];

    for (int k = tid; k < 1024; k += NT) ((int*)s_h4)[k] = 0;
    if (tid < 256) ((float*)s_acc)[tid] = 0.0f;
    if (tid == 0) {
        const float* ip = inp + b * 12;
        float rx = ip[0], ry = ip[1], rz = ip[2];
        float mx = ip[3] * rx, my = ip[4] * ry, mz = ip[5] * rz;
        float sx = ip[6] * rx, sy = ip[7] * ry, sz = ip[8] * rz;
        float aw = __builtin_fmaf(ip[9],  0.84f, 0.01f);
        float a4 = __builtin_fmaf(ip[10], 0.84f, 0.01f);
        float a5 = __builtin_fmaf(ip[11], 0.84f, 0.01f);
        s_par[0] = rx; s_par[1] = ry; s_par[2] = rz;
        s_par[3] = mx; s_par[4] = my; s_par[5] = mz;
        s_par[6] = sx; s_par[7] = sy; s_par[8] = sz;
        s_par[9]  = 0.5f * __builtin_amdgcn_logf(1.0f - aw);
        s_par[10] = 0.5f * __builtin_amdgcn_logf(1.0f - a4);
        s_par[11] = 0.5f * __builtin_amdgcn_logf(1.0f - a5);
        if (g == 0) {
            float dx = mx - sx, dy = my - sy, dz = mz - sz;
            out[(size_t)B * RIRLEN + b] = __builtin_fmaf(
                __builtin_sqrtf(dx * dx + dy * dy + dz * dz), SR_OVER_C, 40.0f);
        }
    }
    __syncthreads();

    if (tid < 96) {
        const int axis = tid >> 5;
        const int j    = tid & 31;
        if (j < 31) {
            const int n = j - 15;
            const float rr = s_par[axis];
            const float mm = s_par[3 + axis];
            const float ss = s_par[6 + axis];
            const float iv = (n & 1) ? __builtin_fmaf(rr, (float)(n + 1), -ss)
                                     : __builtin_fmaf(rr, (float)n, ss);
            const float pv = iv - mm;
            s_p2[axis][j] = pv * pv;
            const float e4 = (float)iabs(n >> 1);
            const float e5 = (float)iabs((n + 1) >> 1);
            const float ex = (axis < 2)
                ? (e4 + e5) * s_par[9]
                : __builtin_fmaf(e4, s_par[10], e5 * s_par[11]);
            s_at[axis][j] = __builtin_amdgcn_exp2f(ex);
        }
    }
    __syncthreads();

    const int fb = 4 * g + 1;

    float2   edh[KPT];
    unsigned ecs[KPT];
    int      enc[KPT];
    #pragma unroll
    for (int k = 0; k < KPT; ++k) {
        enc[k] = -1;
        const int idx = tid + k * NT;
        if (idx < NIMG) {
            const int p  = c_tab.v[idx];
            const int xi = p & 255;
            const int yi = (p >> 8) & 255;
            const int zi = (p >> 16) & 255;
            const float d2   = s_p2[0][xi] + s_p2[1][yi] + s_p2[2][zi];
            const float dist = __builtin_sqrtf(d2);
            const float delay = dist * SR_OVER_C;
            const float di    = __builtin_ceilf(delay);
            const int   ti0   = (int)di - 40;
            const int   bk    = (ti0 + 96) >> 4;
            const bool owned  = ((unsigned)((bk - fb + 64) & 63) < 9u);
            if (ti0 < RIRLEN && owned) {
                const float att = s_at[0][xi] * s_at[1][yi] * s_at[2][zi];
                const float amp = att * __builtin_amdgcn_rcpf(dist);
                float frac = di - delay;
                if (frac == 0.0f) frac = di * 1.52587890625e-05f;
                const int dii = (int)di;
                float c1p = amp * __builtin_amdgcn_sinf(0.5f * frac) * INV_PI;
                if (dii & 1) c1p = -c1p;
                const float Hp     = 0.5f * c1p;
                const float dstore = di - frac;
                const float rv = dstore * 0.0125f;
                const float fr = rv - __builtin_floorf(rv);
                const float Hcd = Hp * __builtin_amdgcn_cosf(fr);
                const float Hsd = Hp * __builtin_amdgcn_sinf(fr);
                const f16x2 pk2 = __builtin_amdgcn_cvt_pkrtz(Hcd, Hsd);
                const int rnk = atomicAdd(&s_h4[bk][q], 1);
                enc[k] = (bk << 13) | rnk;
                edh[k] = make_float2(dstore, Hp);
                ecs[k] = __builtin_bit_cast(unsigned, pk2);
            }
        }
    }
    __syncthreads();

    if (wv == 0) {
        const int l = lane;
        const int4 a0 = *(const int4*)&s_h4[4 * l + 0][0];
        const int4 a1 = *(const int4*)&s_h4[4 * l + 1][0];
        const int4 a2 = *(const int4*)&s_h4[4 * l + 2][0];
        const int4 a3 = *(const int4*)&s_h4[4 * l + 3][0];
        const int c0 = a0.x + a0.y + a0.z + a0.w;
        const int c1 = a1.x + a1.y + a1.z + a1.w;
        const int c2 = a2.x + a2.y + a2.z + a2.w;
        const int c3 = a3.x + a3.y + a3.z + a3.w;
        const int ts = c0 + c1 + c2 + c3;
        int incl = ts;
        #pragma unroll
        for (int d = 1; d < 64; d <<= 1) {
            const int u = __shfl_up(incl, d, 64);
            if (l >= d) incl += u;
        }
        const int base = incl - ts;
        s_off[4 * l + 0] = imin(base, CAP);
        s_off[4 * l + 1] = imin(base + c0, CAP);
        s_off[4 * l + 2] = imin(base + c0 + c1, CAP);
        s_off[4 * l + 3] = imin(base + c0 + c1 + c2, CAP);
        if (l == 63) s_off[256] = imin(incl, CAP);
    }
    __syncthreads();

    if (tid < 256) {
        int run = s_off[tid];
        #pragma unroll
        for (int p = 0; p < 4; ++p) {
            const int c = s_h4[tid][p];
            s_h4[tid][p] = run;
            run += c;
        }
    }
    __syncthreads();

    #pragma unroll
    for (int k = 0; k < KPT; ++k) {
        if (enc[k] >= 0) {
            const int bk   = enc[k] >> 13;
            const int slot = s_h4[bk][q] + (enc[k] & 8191);
            if (slot < CAP) {
                s_dh[slot] = edh[k];
                s_cs[slot] = ecs[k];
            }
        }
    }
    __syncthreads();

    int wlo[4], wlen[4], wpre[4];
    int T = 0, nw = 0;
    #pragma unroll
    for (int kk = 0; kk < 4; ++kk) {
        const int wi = g + 16 * kk;
        wpre[kk] = T;
        if (wi < 62) {
            wlo[kk]  = s_off[4 * wi + 1];
            wlen[kk] = s_off[4 * wi + 10] - wlo[kk];
            T += wlen[kk];
            nw = kk + 1;
        } else { wlo[kk] = 0; wlen[kk] = 0; }
    }
    const int a0r = (T * wv) >> 3;
    const int a1r = (T * (wv + 1)) >> 3;

#define EV1(ACC, DLY, HPV, PKU) do {                                         \
        const f16x2 hh = __builtin_bit_cast(f16x2, (PKU));                   \
        const float xw = tf - (DLY);                                         \
        const float pre = __builtin_fmaf(cth0, (float)hh.x,                  \
                              __builtin_fmaf(sth0, (float)hh.y, (HPV)));     \
        const float hm = (__builtin_fabsf(xw) <= 40.0f) ? pre : 0.0f;        \
        ACC = __builtin_fmaf(hm, __builtin_amdgcn_rcpf(xw), ACC);            \
    } while (0)

    #pragma unroll
    for (int kk = 0; kk < 4; ++kk) {
        if (wlen[kk] == 0) continue;
        const int o0 = imax(wpre[kk], a0r);
        const int oe = imin(wpre[kk] + wlen[kk], a1r);
        if (o0 >= oe) continue;
        int       i  = wlo[kk] + (o0 - wpre[kk]);
        const int ie = wlo[kk] + (oe - wpre[kk]);

        const int   wi   = g + 16 * kk;
        const int   t    = (wi << 6) + lane;
        const float tf   = (float)t;
        const int   m    = t - (t / 80) * 80;
        const float cth0 = __builtin_amdgcn_cosf((float)m * 0.0125f);
        const float sth0 = __builtin_amdgcn_sinf((float)m * 0.0125f);

        float acc0 = 0.0f, acc1 = 0.0f;
        while (i < ie && (i & 3)) { EV1(acc0, s_dh[i].x, s_dh[i].y, s_cs[i]); ++i; }
        for (; i + 4 <= ie; i += 4) {
            const float4 d0 = *(const float4*)&s_dh[i];
            const float4 d1 = *(const float4*)&s_dh[i + 2];
            const uint4  cc = *(const uint4*)&s_cs[i];
            EV1(acc0, d0.x, d0.y, cc.x); EV1(acc1, d0.z, d0.w, cc.y);
            EV1(acc0, d1.x, d1.y, cc.z); EV1(acc1, d1.z, d1.w, cc.w);
        }
        for (; i < ie; ++i) EV1(acc0, s_dh[i].x, s_dh[i].y, s_cs[i]);

        atomicAdd(&s_acc[kk][lane], acc0 + acc1);
    }
#undef EV1
    __syncthreads();

    if (tid < 64 * nw) {
        const int kk = tid >> 6;
        const int wi = g + 16 * kk;
        const int t  = (wi << 6) + lane;
        const float sl = (lane & 1) ? -1.0f : 1.0f;
        out[(size_t)b * RIRLEN + t] = sl * s_acc[kk][lane];
    }
}

extern "C" void kernel_launch(void* const* d_in, const int* in_sizes, int n_in,
                              void* d_out, int out_size, void* d_ws, size_t ws_size,
                              hipStream_t stream) {
    (void)n_in; (void)out_size;
    const float* inp = (const float*)d_in[0];
    float* out = (float*)d_out;
    const int B = in_sizes[0] / 12;

    const size_t dh_bytes   = (size_t)B * NIMG * sizeof(float2);
    const size_t cs_bytes   = (size_t)B * NIMG * sizeof(unsigned);
    const size_t offs_bytes = (size_t)B * 257 * sizeof(int);
    const int use_ws = (d_ws != nullptr &&
                        ws_size >= dh_bytes + cs_bytes + offs_bytes) ? 1 : 0;

    if (use_ws) {
        float2*   wdh  = (float2*)d_ws;
        unsigned* wcs  = (unsigned*)((char*)d_ws + dh_bytes);
        int*      offs = (int*)((char*)d_ws + dh_bytes + cs_bytes);
        rir_prep  <<<dim3(B),        dim3(NTP), 0, stream>>>(inp, out, wdh, wcs, offs, B);
        rir_gather<<<dim3(B * GGRP), dim3(NTG), 0, stream>>>(wdh, wcs, offs, out, B);
    } else {
        rir_fused<<<dim3(B * NGRPF), dim3(NT), 0, stream>>>(inp, out, B);
    }
}

// Round 23
// 96.833 us; speedup vs baseline: 1.0835x; 1.0835x over previous
//
#include <hip/hip_runtime.h>

#define NIMG    4991
#define RIRLEN  3968
#define NT      512          // fallback block: 8 waves
#define NTP     1024         // prep block: 16 waves
#define NTG     256          // gather block: 4 waves
#define NGRPF   16           // fallback blocks per batch
#define GGRP    31           // gather blocks per batch (window pairs {g, 61-g})
#define CAP     2048         // fallback staged capacity
#define CAPG    1152         // gather staged capacity (pair typ ~330, guard 3.5x)
#define KPT     10           // images per thread, NT=512 path
#define KPTP    5            // images per thread, NTP=1024 path
#define INV_PI  0.31830988618379067f
#define SR_OVER_C 46.647230320699704f   // 16000 / 343

// ---- compile-time compact image-source table: all (x,y,z), |x|+|y|+|z| <= 15 ----
struct Tab { int v[NIMG]; };
static constexpr Tab make_tab() {
    Tab t{};
    int k = 0;
    for (int x = -15; x <= 15; ++x)
        for (int y = -15; y <= 15; ++y)
            for (int z = -15; z <= 15; ++z) {
                int ax = x < 0 ? -x : x;
                int ay = y < 0 ? -y : y;
                int az = z < 0 ? -z : z;
                if (ax + ay + az <= 15)
                    t.v[k++] = (x + 15) | ((y + 15) << 8) | ((z + 15) << 16);
            }
    return t;
}
__constant__ Tab c_tab = make_tab();

static __device__ __forceinline__ int iabs(int v) { return v < 0 ? -v : v; }
static __device__ __forceinline__ int imin(int a, int b) { return a < b ? a : b; }
static __device__ __forceinline__ int imax(int a, int b) { return a > b ? a : b; }

// __builtin_amdgcn_cvt_pkrtz returns __fp16-based ext vector (R10 lesson).
typedef __fp16 f16x2 __attribute__((ext_vector_type(2)));

// ============================================================================
// v31 = v29 + (A) COMPLEMENTARY WINDOW PAIRING + (B) F32 16-BYTE ENTRIES.
// R22 decomposition: gather 44.3us = 12us issue floor x 1.6 (issue ineff.)
// x 2.3 (occupancy 43% = drain/imbalance). (A) block g owns windows
// {g, 61-g}: shell density rises with delay, so light-early + heavy-late
// sums are near-constant -> per-block work uniform (R5 snake, block level).
// (B) entry = float4 {dstore, Hp, Hcd, Hsd}: no f16 cvts (9->7 slots/EVAL),
// every LDS read a natural b128, no alignment prologue. LDS 18.9KB -> still
// 8 blocks/CU. Prep identical except float4 writes; fallback = R19 verbatim.
// Math (verified R9-R22): v(t) = (-1)^t*(Hp + cth0*Hcd + sth0*Hsd)/(t-dstore),
// |xw|<=40 mask; xw==0 impossible (Sterbenz / rel nudge di*2^-16).
// ============================================================================

// ---- K1: once-per-batch prep: geometry + bucket-sort into ws ----
__global__ __launch_bounds__(NTP)
void rir_prep(const float* __restrict__ inp, float* __restrict__ out,
              float4* __restrict__ wq, int* __restrict__ offs, int B) {
    const int b    = blockIdx.x;
    const int tid  = threadIdx.x;
    const int lane = tid & 63;
    const int wv   = tid >> 6;
    const int q    = lane & 3;

    __shared__ float s_par[12];
    __shared__ float s_p2[3][32];
    __shared__ float s_at[3][32];
    __shared__ int   s_h4[256][4];
    __shared__ int   s_off[257];

    if (tid < 1024) ((int*)s_h4)[tid] = 0;
    if (tid == 0) {
        const float* ip = inp + b * 12;
        float rx = ip[0], ry = ip[1], rz = ip[2];
        float mx = ip[3] * rx, my = ip[4] * ry, mz = ip[5] * rz;
        float sx = ip[6] * rx, sy = ip[7] * ry, sz = ip[8] * rz;
        float aw = __builtin_fmaf(ip[9],  0.84f, 0.01f);
        float a4 = __builtin_fmaf(ip[10], 0.84f, 0.01f);
        float a5 = __builtin_fmaf(ip[11], 0.84f, 0.01f);
        s_par[0] = rx; s_par[1] = ry; s_par[2] = rz;
        s_par[3] = mx; s_par[4] = my; s_par[5] = mz;
        s_par[6] = sx; s_par[7] = sy; s_par[8] = sz;
        s_par[9]  = 0.5f * __builtin_amdgcn_logf(1.0f - aw);   // log2(tr)
        s_par[10] = 0.5f * __builtin_amdgcn_logf(1.0f - a4);
        s_par[11] = 0.5f * __builtin_amdgcn_logf(1.0f - a5);
        float dx = mx - sx, dy = my - sy, dz = mz - sz;
        out[(size_t)B * RIRLEN + b] = __builtin_fmaf(
            __builtin_sqrtf(dx * dx + dy * dy + dz * dz), SR_OVER_C, 40.0f);
    }
    __syncthreads();

    if (tid < 96) {                          // per-axis tables
        const int axis = tid >> 5;
        const int j    = tid & 31;
        if (j < 31) {
            const int n = j - 15;
            const float rr = s_par[axis];
            const float mm = s_par[3 + axis];
            const float ss = s_par[6 + axis];
            const float iv = (n & 1) ? __builtin_fmaf(rr, (float)(n + 1), -ss)
                                     : __builtin_fmaf(rr, (float)n, ss);
            const float pv = iv - mm;
            s_p2[axis][j] = pv * pv;
            const float e4 = (float)iabs(n >> 1);
            const float e5 = (float)iabs((n + 1) >> 1);
            const float ex = (axis < 2)
                ? (e4 + e5) * s_par[9]
                : __builtin_fmaf(e4, s_par[10], e5 * s_par[11]);
            s_at[axis][j] = __builtin_amdgcn_exp2f(ex);
        }
    }
    __syncthreads();

    // single geometry pass -> registers; histogram returns rank
    float4 ef[KPTP];
    int    enc[KPTP];
    #pragma unroll
    for (int k = 0; k < KPTP; ++k) {
        enc[k] = -1;
        const int idx = tid + k * NTP;
        if (idx < NIMG) {
            const int p  = c_tab.v[idx];
            const int xi = p & 255;
            const int yi = (p >> 8) & 255;
            const int zi = (p >> 16) & 255;
            const float d2   = s_p2[0][xi] + s_p2[1][yi] + s_p2[2][zi];
            const float dist = __builtin_sqrtf(d2);
            const float delay = dist * SR_OVER_C;
            const float di    = __builtin_ceilf(delay);
            const int   ti0   = (int)di - 40;
            if (ti0 < RIRLEN) {
                const int bk = (ti0 + 96) >> 4;                // in [3,253]
                const float att = s_at[0][xi] * s_at[1][yi] * s_at[2][zi];
                const float amp = att * __builtin_amdgcn_rcpf(dist);
                float frac = di - delay;                       // exact (Sterbenz)
                if (frac == 0.0f) frac = di * 1.52587890625e-05f;
                const int dii = (int)di;
                float c1p = amp * __builtin_amdgcn_sinf(0.5f * frac) * INV_PI;
                if (dii & 1) c1p = -c1p;
                const float Hp     = 0.5f * c1p;
                const float dstore = di - frac;
                const float rv = dstore * 0.0125f;
                const float fr = rv - __builtin_floorf(rv);
                const float Hcd = Hp * __builtin_amdgcn_cosf(fr);
                const float Hsd = Hp * __builtin_amdgcn_sinf(fr);

                const int rnk = atomicAdd(&s_h4[bk][q], 1);
                enc[k] = (bk << 13) | rnk;
                ef[k]  = make_float4(dstore, Hp, Hcd, Hsd);
            }
        }
    }
    __syncthreads();

    if (wv == 0) {                           // single-wave shuffle scan
        const int l = lane;
        const int4 a0 = *(const int4*)&s_h4[4 * l + 0][0];
        const int4 a1 = *(const int4*)&s_h4[4 * l + 1][0];
        const int4 a2 = *(const int4*)&s_h4[4 * l + 2][0];
        const int4 a3 = *(const int4*)&s_h4[4 * l + 3][0];
        const int c0 = a0.x + a0.y + a0.z + a0.w;
        const int c1 = a1.x + a1.y + a1.z + a1.w;
        const int c2 = a2.x + a2.y + a2.z + a2.w;
        const int c3 = a3.x + a3.y + a3.z + a3.w;
        const int ts = c0 + c1 + c2 + c3;
        int incl = ts;
        #pragma unroll
        for (int d = 1; d < 64; d <<= 1) {
            const int u = __shfl_up(incl, d, 64);
            if (l >= d) incl += u;
        }
        const int base = incl - ts;
        s_off[4 * l + 0] = base;
        s_off[4 * l + 1] = base + c0;
        s_off[4 * l + 2] = base + c0 + c1;
        s_off[4 * l + 3] = base + c0 + c1 + c2;
        if (l == 63) s_off[256] = incl;
    }
    __syncthreads();

    if (tid < 256) {                         // counts -> base cursors
        int run = s_off[tid];
        #pragma unroll
        for (int p = 0; p < 4; ++p) {
            const int c = s_h4[tid][p];
            s_h4[tid][p] = run;
            run += c;
        }
    }
    __syncthreads();

    // scatter to GLOBAL ws (rank + base, plain stores)
    float4* qb = wq + (size_t)b * NIMG;
    #pragma unroll
    for (int k = 0; k < KPTP; ++k) {
        if (enc[k] >= 0) {
            const int bk   = enc[k] >> 13;
            const int slot = s_h4[bk][q] + (enc[k] & 8191);
            qb[slot] = ef[k];
        }
    }
    if (tid < 257) offs[b * 257 + tid] = s_off[tid];
}

// ---- K2: gather: complementary window pair {g, 61-g}, f32 b128 entries ----
__global__ __launch_bounds__(NTG, 8)
void rir_gather(const float4* __restrict__ wq, const int* __restrict__ offs,
                float* __restrict__ out, int B) {
    const int bx   = blockIdx.x;
    const int b    = bx / GGRP;
    const int g    = bx - b * GGRP;          // 0..30
    const int tid  = threadIdx.x;
    const int lane = tid & 63;
    const int wv   = tid >> 6;               // 0..3

    __shared__ __align__(16) float4 s_e[CAPG];      // staged entries (18.4KB)
    __shared__ float s_acc[2][64];                  // per-window accum

    if (tid < 128) ((float*)s_acc)[tid] = 0.0f;

    // window pair: wi0 = g (light-early), wi1 = 61-g (heavy-late)
    const int wis[2] = { g, 61 - g };
    const int* ob = offs + b * 257;
    int wlo[2], wlen[2], wpre[2];
    int T = 0;
    #pragma unroll
    for (int kk = 0; kk < 2; ++kk) {
        const int wi = wis[kk];
        wpre[kk] = T;
        wlo[kk]  = ob[4 * wi + 1];
        int len  = ob[4 * wi + 10] - wlo[kk];
        if (T + len > CAPG) len = CAPG - T;  // truncation guard (~impossible)
        if (len < 0) len = 0;
        wlen[kk] = len;
        T += len;
    }

    // stage spans (concatenated) global -> LDS, coalesced within spans
    const float4* qb = wq + (size_t)b * NIMG;
    for (int j = tid; j < T; j += NTG) {
        const int kk  = (j >= wpre[1] && wlen[1] > 0) ? 1 : 0;
        s_e[j] = qb[wlo[kk] + (j - wpre[kk])];
    }
    __syncthreads();

    const int a0r = (T * wv) >> 2;           // this wave's slice [a0r, a1r)
    const int a1r = (T * (wv + 1)) >> 2;

#define EV1(ACC, E) do {                                                     \
        const float xw  = tf - (E).x;                                        \
        const float pre = __builtin_fmaf(cth0, (E).z,                        \
                              __builtin_fmaf(sth0, (E).w, (E).y));           \
        const float hm  = (__builtin_fabsf(xw) <= 40.0f) ? pre : 0.0f;       \
        ACC = __builtin_fmaf(hm, __builtin_amdgcn_rcpf(xw), ACC);            \
    } while (0)

    #pragma unroll
    for (int kk = 0; kk < 2; ++kk) {
        if (wlen[kk] == 0) continue;
        int       i  = imax(wpre[kk], a0r);
        const int ie = imin(wpre[kk] + wlen[kk], a1r);
        if (i >= ie) continue;

        const int   wi   = wis[kk];
        const int   t    = (wi << 6) + lane;
        const float tf   = (float)t;
        const int   m    = t - (t / 80) * 80;           // t mod 80
        const float cth0 = __builtin_amdgcn_cosf((float)m * 0.0125f);
        const float sth0 = __builtin_amdgcn_sinf((float)m * 0.0125f);

        float acc0 = 0.0f, acc1 = 0.0f;
        for (; i + 4 <= ie; i += 4) {        // 4 images / iter = 4 b128 reads
            const float4 e0 = s_e[i],     e1 = s_e[i + 1];
            const float4 e2 = s_e[i + 2], e3 = s_e[i + 3];
            EV1(acc0, e0); EV1(acc1, e1); EV1(acc0, e2); EV1(acc1, e3);
        }
        for (; i < ie; ++i) { const float4 e = s_e[i]; EV1(acc0, e); }

        atomicAdd(&s_acc[kk][lane], acc0 + acc1);
    }
#undef EV1
    __syncthreads();

    if (tid < 128) {
        const int kk = tid >> 6;
        const int wi = wis[kk];
        const int t  = (wi << 6) + lane;
        const float sl = (lane & 1) ? -1.0f : 1.0f;     // wi*64 even
        out[(size_t)b * RIRLEN + t] = sl * s_acc[kk][lane];
    }
}

// ============================================================================
// Fallback (!use_ws): R19's verified single fused kernel, verbatim.
// ============================================================================
__global__ __launch_bounds__(NT, 8)
void rir_fused(const float* __restrict__ inp, float* __restrict__ out, int B) {
    const int bx   = blockIdx.x;
    const int b    = bx >> 4;
    const int g    = bx & 15;
    const int tid  = threadIdx.x;
    const int lane = tid & 63;
    const int wv   = tid >> 6;
    const int q    = lane & 3;

    __shared__ __align__(16) float2   s_dh[CAP];
    __shared__ __align__(16) unsigned s_cs[CAP];
    __shared__ float    s_par[12];
    __shared__ float    s_p2[3][32];
    __shared__ float    s_at[3][32];
    __shared__ int      s_h4[256][4];
    __shared__ int      s_off[257];
    __shared__ float    s_acc[4][64];

    for (int k = tid; k < 1024; k += NT) ((int*)s_h4)[k] = 0;
    if (tid < 256) ((float*)s_acc)[tid] = 0.0f;
    if (tid == 0) {
        const float* ip = inp + b * 12;
        float rx = ip[0], ry = ip[1], rz = ip[2];
        float mx = ip[3] * rx, my = ip[4] * ry, mz = ip[5] * rz;
        float sx = ip[6] * rx, sy = ip[7] * ry, sz = ip[8] * rz;
        float aw = __builtin_fmaf(ip[9],  0.84f, 0.01f);
        float a4 = __builtin_fmaf(ip[10], 0.84f, 0.01f);
        float a5 = __builtin_fmaf(ip[11], 0.84f, 0.01f);
        s_par[0] = rx; s_par[1] = ry; s_par[2] = rz;
        s_par[3] = mx; s_par[4] = my; s_par[5] = mz;
        s_par[6] = sx; s_par[7] = sy; s_par[8] = sz;
        s_par[9]  = 0.5f * __builtin_amdgcn_logf(1.0f - aw);
        s_par[10] = 0.5f * __builtin_amdgcn_logf(1.0f - a4);
        s_par[11] = 0.5f * __builtin_amdgcn_logf(1.0f - a5);
        if (g == 0) {
            float dx = mx - sx, dy = my - sy, dz = mz - sz;
            out[(size_t)B * RIRLEN + b] = __builtin_fmaf(
                __builtin_sqrtf(dx * dx + dy * dy + dz * dz), SR_OVER_C, 40.0f);
        }
    }
    __syncthreads();

    if (tid < 96) {
        const int axis = tid >> 5;
        const int j    = tid & 31;
        if (j < 31) {
            const int n = j - 15;
            const float rr = s_par[axis];
            const float mm = s_par[3 + axis];
            const float ss = s_par[6 + axis];
            const float iv = (n & 1) ? __builtin_fmaf(rr, (float)(n + 1), -ss)
                                     : __builtin_fmaf(rr, (float)n, ss);
            const float pv = iv - mm;
            s_p2[axis][j] = pv * pv;
            const float e4 = (float)iabs(n >> 1);
            const float e5 = (float)iabs((n + 1) >> 1);
            const float ex = (axis < 2)
                ? (e4 + e5) * s_par[9]
                : __builtin_fmaf(e4, s_par[10], e5 * s_par[11]);
            s_at[axis][j] = __builtin_amdgcn_exp2f(ex);
        }
    }
    __syncthreads();

    const int fb = 4 * g + 1;

    float2   edh[KPT];
    unsigned ecs[KPT];
    int      enc[KPT];
    #pragma unroll
    for (int k = 0; k < KPT; ++k) {
        enc[k] = -1;
        const int idx = tid + k * NT;
        if (idx < NIMG) {
            const int p  = c_tab.v[idx];
            const int xi = p & 255;
            const int yi = (p >> 8) & 255;
            const int zi = (p >> 16) & 255;
            const float d2   = s_p2[0][xi] + s_p2[1][yi] + s_p2[2][zi];
            const float dist = __builtin_sqrtf(d2);
            const float delay = dist * SR_OVER_C;
            const float di    = __builtin_ceilf(delay);
            const int   ti0   = (int)di - 40;
            const int   bk    = (ti0 + 96) >> 4;
            const bool owned  = ((unsigned)((bk - fb + 64) & 63) < 9u);
            if (ti0 < RIRLEN && owned) {
                const float att = s_at[0][xi] * s_at[1][yi] * s_at[2][zi];
                const float amp = att * __builtin_amdgcn_rcpf(dist);
                float frac = di - delay;
                if (frac == 0.0f) frac = di * 1.52587890625e-05f;
                const int dii = (int)di;
                float c1p = amp * __builtin_amdgcn_sinf(0.5f * frac) * INV_PI;
                if (dii & 1) c1p = -c1p;
                const float Hp     = 0.5f * c1p;
                const float dstore = di - frac;
                const float rv = dstore * 0.0125f;
                const float fr = rv - __builtin_floorf(rv);
                const float Hcd = Hp * __builtin_amdgcn_cosf(fr);
                const float Hsd = Hp * __builtin_amdgcn_sinf(fr);
                const f16x2 pk2 = __builtin_amdgcn_cvt_pkrtz(Hcd, Hsd);
                const int rnk = atomicAdd(&s_h4[bk][q], 1);
                enc[k] = (bk << 13) | rnk;
                edh[k] = make_float2(dstore, Hp);
                ecs[k] = __builtin_bit_cast(unsigned, pk2);
            }
        }
    }
    __syncthreads();

    if (wv == 0) {
        const int l = lane;
        const int4 a0 = *(const int4*)&s_h4[4 * l + 0][0];
        const int4 a1 = *(const int4*)&s_h4[4 * l + 1][0];
        const int4 a2 = *(const int4*)&s_h4[4 * l + 2][0];
        const int4 a3 = *(const int4*)&s_h4[4 * l + 3][0];
        const int c0 = a0.x + a0.y + a0.z + a0.w;
        const int c1 = a1.x + a1.y + a1.z + a1.w;
        const int c2 = a2.x + a2.y + a2.z + a2.w;
        const int c3 = a3.x + a3.y + a3.z + a3.w;
        const int ts = c0 + c1 + c2 + c3;
        int incl = ts;
        #pragma unroll
        for (int d = 1; d < 64; d <<= 1) {
            const int u = __shfl_up(incl, d, 64);
            if (l >= d) incl += u;
        }
        const int base = incl - ts;
        s_off[4 * l + 0] = imin(base, CAP);
        s_off[4 * l + 1] = imin(base + c0, CAP);
        s_off[4 * l + 2] = imin(base + c0 + c1, CAP);
        s_off[4 * l + 3] = imin(base + c0 + c1 + c2, CAP);
        if (l == 63) s_off[256] = imin(incl, CAP);
    }
    __syncthreads();

    if (tid < 256) {
        int run = s_off[tid];
        #pragma unroll
        for (int p = 0; p < 4; ++p) {
            const int c = s_h4[tid][p];
            s_h4[tid][p] = run;
            run += c;
        }
    }
    __syncthreads();

    #pragma unroll
    for (int k = 0; k < KPT; ++k) {
        if (enc[k] >= 0) {
            const int bk   = enc[k] >> 13;
            const int slot = s_h4[bk][q] + (enc[k] & 8191);
            if (slot < CAP) {
                s_dh[slot] = edh[k];
                s_cs[slot] = ecs[k];
            }
        }
    }
    __syncthreads();

    int wlo[4], wlen[4], wpre[4];
    int T = 0, nw = 0;
    #pragma unroll
    for (int kk = 0; kk < 4; ++kk) {
        const int wi = g + 16 * kk;
        wpre[kk] = T;
        if (wi < 62) {
            wlo[kk]  = s_off[4 * wi + 1];
            wlen[kk] = s_off[4 * wi + 10] - wlo[kk];
            T += wlen[kk];
            nw = kk + 1;
        } else { wlo[kk] = 0; wlen[kk] = 0; }
    }
    const int a0r = (T * wv) >> 3;
    const int a1r = (T * (wv + 1)) >> 3;

#define EV1(ACC, DLY, HPV, PKU) do {                                         \
        const f16x2 hh = __builtin_bit_cast(f16x2, (PKU));                   \
        const float xw = tf - (DLY);                                         \
        const float pre = __builtin_fmaf(cth0, (float)hh.x,                  \
                              __builtin_fmaf(sth0, (float)hh.y, (HPV)));     \
        const float hm = (__builtin_fabsf(xw) <= 40.0f) ? pre : 0.0f;        \
        ACC = __builtin_fmaf(hm, __builtin_amdgcn_rcpf(xw), ACC);            \
    } while (0)

    #pragma unroll
    for (int kk = 0; kk < 4; ++kk) {
        if (wlen[kk] == 0) continue;
        const int o0 = imax(wpre[kk], a0r);
        const int oe = imin(wpre[kk] + wlen[kk], a1r);
        if (o0 >= oe) continue;
        int       i  = wlo[kk] + (o0 - wpre[kk]);
        const int ie = wlo[kk] + (oe - wpre[kk]);

        const int   wi   = g + 16 * kk;
        const int   t    = (wi << 6) + lane;
        const float tf   = (float)t;
        const int   m    = t - (t / 80) * 80;
        const float cth0 = __builtin_amdgcn_cosf((float)m * 0.0125f);
        const float sth0 = __builtin_amdgcn_sinf((float)m * 0.0125f);

        float acc0 = 0.0f, acc1 = 0.0f;
        while (i < ie && (i & 3)) { EV1(acc0, s_dh[i].x, s_dh[i].y, s_cs[i]); ++i; }
        for (; i + 4 <= ie; i += 4) {
            const float4 d0 = *(const float4*)&s_dh[i];
            const float4 d1 = *(const float4*)&s_dh[i + 2];
            const uint4  cc = *(const uint4*)&s_cs[i];
            EV1(acc0, d0.x, d0.y, cc.x); EV1(acc1, d0.z, d0.w, cc.y);
            EV1(acc0, d1.x, d1.y, cc.z); EV1(acc1, d1.z, d1.w, cc.w);
        }
        for (; i < ie; ++i) EV1(acc0, s_dh[i].x, s_dh[i].y, s_cs[i]);

        atomicAdd(&s_acc[kk][lane], acc0 + acc1);
    }
#undef EV1
    __syncthreads();

    if (tid < 64 * nw) {
        const int kk = tid >> 6;
        const int wi = g + 16 * kk;
        const int t  = (wi << 6) + lane;
        const float sl = (lane & 1) ? -1.0f : 1.0f;
        out[(size_t)b * RIRLEN + t] = sl * s_acc[kk][lane];
    }
}

extern "C" void kernel_launch(void* const* d_in, const int* in_sizes, int n_in,
                              void* d_out, int out_size, void* d_ws, size_t ws_size,
                              hipStream_t stream) {
    (void)n_in; (void)out_size;
    const float* inp = (const float*)d_in[0];
    float* out = (float*)d_out;
    const int B = in_sizes[0] / 12;

    const size_t wq_bytes   = (size_t)B * NIMG * sizeof(float4);
    const size_t offs_bytes = (size_t)B * 257 * sizeof(int);
    const int use_ws = (d_ws != nullptr && ws_size >= wq_bytes + offs_bytes) ? 1 : 0;

    if (use_ws) {
        float4* wq   = (float4*)d_ws;
        int*    offs = (int*)((char*)d_ws + wq_bytes);
        rir_prep  <<<dim3(B),        dim3(NTP), 0, stream>>>(inp, out, wq, offs, B);
        rir_gather<<<dim3(B * GGRP), dim3(NTG), 0, stream>>>(wq, offs, out, B);
    } else {
        rir_fused<<<dim3(B * NGRPF), dim3(NT), 0, stream>>>(inp, out, B);
    }
}